// Round 1
// 177.628 us; speedup vs baseline: 1.0712x; 1.0712x over previous
//
#include <hip/hip_runtime.h>
#include <hip/hip_bf16.h>
#include <math.h>

// B=2, L=2048, D=1024, H=16, HD=64
#define NB_L 2048
#define GM 4096          // B*L rows
#define GN 3072          // 3*D cols
#define GK 1024
#define NROWS 65536      // B*H*L partial rows per split
#define SCALE_L2E 0.180336880f   // 0.125 * log2(e), folded into Q at GEMM epilogue

typedef float  f4v __attribute__((ext_vector_type(4)));
typedef short  s4v __attribute__((ext_vector_type(4)));
typedef short  s8v __attribute__((ext_vector_type(8)));

#define MFMA_16x16x32(a, b, c) __builtin_amdgcn_mfma_f32_16x16x32_bf16((a), (b), (c), 0, 0, 0)
#define MFMA_16x16x16(a, b, c) __builtin_amdgcn_mfma_f32_16x16x16bf16_1k((a), (b), (c), 0, 0, 0)

static __device__ __forceinline__ unsigned int bfpk(float a, float b) {
    __hip_bfloat162 h = __float22bfloat162_rn(float2{a, b});
    union { __hip_bfloat162 h2; unsigned int u; } cv; cv.h2 = h; return cv.u;
}
static __device__ __forceinline__ unsigned short bf1(float a) {
    union { __hip_bfloat16 h; unsigned short u; } cv; cv.h = __float2bfloat16(a); return cv.u;
}
static __device__ __forceinline__ float bf2f(unsigned short u) {
    union { unsigned int u; float f; } cv; cv.u = ((unsigned int)u) << 16; return cv.f;
}

// async global->LDS, 16B per lane
static __device__ __forceinline__ void gl_lds16(const ushort* g, ushort* l) {
    __builtin_amdgcn_global_load_lds((const __attribute__((address_space(1))) void*)g,
                                     (__attribute__((address_space(3))) void*)l, 16, 0, 0);
}

// ---------------------------------------------------------------------------
// Fused input prep: blocks [0,2048) convert X f32->bf16; blocks [2048,2816)
// convert+transpose W -> Wt [3072,1024] bf16 (k contiguous).
// ---------------------------------------------------------------------------
__global__ __launch_bounds__(256) void conv_fused(
    const float* __restrict__ X, const float* __restrict__ W,
    ushort* __restrict__ Xb, ushort* __restrict__ Wt)
{
    __shared__ __align__(16) ushort T[64][72];
    const int bid = blockIdx.x, t = threadIdx.x;
    if (bid < 2048) {
        const int i = bid * 256 + t;
        const float4 f0 = ((const float4*)X)[2 * i];
        const float4 f1 = ((const float4*)X)[2 * i + 1];
        uint4 u;
        u.x = bfpk(f0.x, f0.y); u.y = bfpk(f0.z, f0.w);
        u.z = bfpk(f1.x, f1.y); u.w = bfpk(f1.z, f1.w);
        ((uint4*)Xb)[i] = u;
    } else {
        const int wb = bid - 2048;                 // 0..767
        const int k0 = (wb & 15) * 64, n0 = (wb >> 4) * 64;
        {
            const int kr = t >> 2, nc0 = (t & 3) * 16;
            const float* src = W + (size_t)(k0 + kr) * GN + n0 + nc0;
#pragma unroll
            for (int u = 0; u < 4; ++u) {
                const float4 v = *(const float4*)(src + 4 * u);
                T[nc0 + 4 * u + 0][kr] = bf1(v.x);
                T[nc0 + 4 * u + 1][kr] = bf1(v.y);
                T[nc0 + 4 * u + 2][kr] = bf1(v.z);
                T[nc0 + 4 * u + 3][kr] = bf1(v.w);
            }
        }
        __syncthreads();
        {
            const int nr = t >> 2, kc0 = (t & 3) * 16;
            ushort* dst = Wt + (size_t)(n0 + nr) * GK + k0 + kc0;
            *(s8v*)dst       = *(const s8v*)&T[nr][kc0];
            *(s8v*)(dst + 8) = *(const s8v*)&T[nr][kc0 + 8];
        }
    }
}

// ---------------------------------------------------------------------------
// bf16 MFMA GEMM — 256x256 tile, BK=64, 512 thr (8 waves 2Mx4N), 128 KiB LDS,
// 8-phase counted-vmcnt schedule (T2+T3+T4+T5 port of the m201 template).
//
// LDS unit = K-half (256 rows x 32 k = 16 KB), 2 issues of global_load_lds/16B.
// Double-buffered by K-tile (64 k). Per K-tile: 4 phases
//   ph0: read B[ks0]x4 + A[M0-3,ks0]x4, stage B-kh1(t+1);  16 MFMA (M0-3,ks0)
//   ph1: read A[M4-7,ks0]x4 (B reused), stage A-kh1(t+1);  16 MFMA (M4-7,ks0)
//   ph2: read B[ks1]x4 + A[M0-3,ks1]x4, stage A-kh0(t+2);  16 MFMA (M0-3,ks1)
//   ph3: read A[M4-7,ks1]x4,            stage B-kh0(t+2);  16 MFMA (M4-7,ks1)
// each phase: {ds_reads; stage; s_barrier; lgkmcnt(0); setprio(1); MFMAs;
// setprio(0); s_barrier}.  ONE vmcnt(4) per K-tile (before ph3's end barrier):
// only the newest 2 half-tiles (t+2 kh0 pair) may stay in flight across the
// group boundary -> loads are never drained to 0 in steady state.
// kh0(t+2) overwrites the CURRENT buffer's kh0 region, which is safe because
// its last readers are ph0/ph1 and the issue happens after ph1's end barrier.
//
// Bank conflicts: [256][32] row-major bf16 would put all 16 lq-lanes of a
// frag read in 2 banks (64B row stride). XOR the 16B-chunk index with
// (row>>1)&3: each bank then serves exactly 2 lanes (free, m136). Applied as
// inverse-swizzled GLOBAL source + swizzled ds_read (linear gl_lds dest).
//
// Grid 192 (16x12 tiles of 256), %8==0 XCD region swizzle: each XCD owns a
// 4x6 tile region (A 2MB + B 3MB ~ L2-resident per XCD).
// Epilogue: identical attention-native layouts as before:
//   Qh[bh][q][d] (pre-scaled), Kh[bh][k][d^((k&7)<<3)], VT[bh][d][k^((d&7)<<3)]
// ---------------------------------------------------------------------------
__global__ __launch_bounds__(512, 2) void qkv_gemm_bf16(
    const ushort* __restrict__ Xb, const ushort* __restrict__ Wt,
    ushort* __restrict__ Qh, ushort* __restrict__ Kh, ushort* __restrict__ VT)
{
    __shared__ __align__(16) ushort As[2][2][256][32];   // [buf][khalf][row][k]
    __shared__ __align__(16) ushort Bs[2][2][256][32];

    const int tid = threadIdx.x;
    const int bid = blockIdx.x;

    // XCD region swizzle: xcd = bid%8 owns a 4(y) x 6(x) tile region
    const int xcd = bid & 7, idx = bid >> 3;             // idx in [0,24)
    const int ytile = ((xcd >> 1) << 2) + (idx & 3);     // 0..15
    const int xtile = (xcd & 1) * 6 + (idx >> 2);        // 0..11
    const int row0 = ytile << 8, col0 = xtile << 8;

    const int lane = tid & 63, w = tid >> 6;
    const int wm = w >> 2, wn = w & 3;                   // 2 x 4 wave grid
    const int lq = lane & 15, quad = lane >> 4;

    // staging decomposition: thread -> (row rA, physical 16B chunk pA)
    const int rA = tid >> 2, pA = tid & 3;
    const int cA = pA ^ ((rA >> 1) & 3);                 // logical chunk (inverse swizzle)
    const ushort* gA0 = Xb + (size_t)(row0 + rA) * GK + cA * 8;
    const ushort* gB0 = Wt + (size_t)(col0 + rA) * GK + cA * 8;

    // frag-read physical chunk (element offset within 32-k row)
    const int pq = (quad ^ ((lq >> 1) & 3)) * 8;
    const int rowA = wm * 128 + lq;
    const int rowB = wn * 64 + lq;

    f4v acc[8][4];
#pragma unroll
    for (int mf = 0; mf < 8; ++mf)
#pragma unroll
        for (int nf = 0; nf < 4; ++nf) acc[mf][nf] = 0.f;

    auto stA = [&](int t, int h, int u) {
        gl_lds16(gA0 + (size_t)u * 128 * GK + t * 64 + h * 32,
                 &As[t & 1][h][u * 128 + rA][pA * 8]);
    };
    auto stB = [&](int t, int h, int u) {
        gl_lds16(gB0 + (size_t)u * 128 * GK + t * 64 + h * 32,
                 &Bs[t & 1][h][u * 128 + rA][pA * 8]);
    };

    // prologue: t0 fully + t1 kh0; allow t1-kh0 (newest 2 halves) in flight
    stA(0, 0, 0); stA(0, 0, 1);
    stB(0, 0, 0); stB(0, 0, 1);
    stB(0, 1, 0); stB(0, 1, 1);
    stA(0, 1, 0); stA(0, 1, 1);
    stA(1, 0, 0); stA(1, 0, 1);
    stB(1, 0, 0); stB(1, 0, 1);
    asm volatile("s_waitcnt vmcnt(4)" ::: "memory");
    __builtin_amdgcn_s_barrier();
    asm volatile("" ::: "memory");

    const int NT = GK / 64;   // 16
#pragma unroll 2
    for (int t = 0; t < NT; ++t) {
        const int cur = t & 1;
        s8v af[4], bfr[4];

        // ---- phase 0: ks0, M0-3 ----
#pragma unroll
        for (int nf = 0; nf < 4; ++nf) bfr[nf] = *(const s8v*)&Bs[cur][0][rowB + nf * 16][pq];
#pragma unroll
        for (int mf = 0; mf < 4; ++mf) af[mf] = *(const s8v*)&As[cur][0][rowA + mf * 16][pq];
        if (t + 1 < NT) { stB(t + 1, 1, 0); stB(t + 1, 1, 1); }
        __builtin_amdgcn_s_barrier();
        asm volatile("s_waitcnt lgkmcnt(0)");
        __builtin_amdgcn_s_setprio(1);
#pragma unroll
        for (int mf = 0; mf < 4; ++mf)
#pragma unroll
            for (int nf = 0; nf < 4; ++nf)
                acc[mf][nf] = MFMA_16x16x32(af[mf], bfr[nf], acc[mf][nf]);
        __builtin_amdgcn_s_setprio(0);
        __builtin_amdgcn_s_barrier();

        // ---- phase 1: ks0, M4-7 (B frags reused) ----
#pragma unroll
        for (int mf = 0; mf < 4; ++mf) af[mf] = *(const s8v*)&As[cur][0][rowA + 64 + mf * 16][pq];
        if (t + 1 < NT) { stA(t + 1, 1, 0); stA(t + 1, 1, 1); }
        __builtin_amdgcn_s_barrier();
        asm volatile("s_waitcnt lgkmcnt(0)");
        __builtin_amdgcn_s_setprio(1);
#pragma unroll
        for (int mf = 0; mf < 4; ++mf)
#pragma unroll
            for (int nf = 0; nf < 4; ++nf)
                acc[mf + 4][nf] = MFMA_16x16x32(af[mf], bfr[nf], acc[mf + 4][nf]);
        __builtin_amdgcn_s_setprio(0);
        __builtin_amdgcn_s_barrier();

        // ---- phase 2: ks1, M0-3 ----
#pragma unroll
        for (int nf = 0; nf < 4; ++nf) bfr[nf] = *(const s8v*)&Bs[cur][1][rowB + nf * 16][pq];
#pragma unroll
        for (int mf = 0; mf < 4; ++mf) af[mf] = *(const s8v*)&As[cur][1][rowA + mf * 16][pq];
        if (t + 2 < NT) { stA(t + 2, 0, 0); stA(t + 2, 0, 1); }   // into cur buf kh0 (safe: last read ph1)
        __builtin_amdgcn_s_barrier();
        asm volatile("s_waitcnt lgkmcnt(0)");
        __builtin_amdgcn_s_setprio(1);
#pragma unroll
        for (int mf = 0; mf < 4; ++mf)
#pragma unroll
            for (int nf = 0; nf < 4; ++nf)
                acc[mf][nf] = MFMA_16x16x32(af[mf], bfr[nf], acc[mf][nf]);
        __builtin_amdgcn_s_setprio(0);
        __builtin_amdgcn_s_barrier();

        // ---- phase 3: ks1, M4-7 ----
#pragma unroll
        for (int mf = 0; mf < 4; ++mf) af[mf] = *(const s8v*)&As[cur][1][rowA + 64 + mf * 16][pq];
        if (t + 2 < NT) { stB(t + 2, 0, 0); stB(t + 2, 0, 1); }
        __builtin_amdgcn_s_barrier();
        asm volatile("s_waitcnt lgkmcnt(0)");
        __builtin_amdgcn_s_setprio(1);
#pragma unroll
        for (int mf = 0; mf < 4; ++mf)
#pragma unroll
            for (int nf = 0; nf < 4; ++nf)
                acc[mf + 4][nf] = MFMA_16x16x32(af[mf], bfr[nf], acc[mf + 4][nf]);
        __builtin_amdgcn_s_setprio(0);
        // group-end wait: keep t+2-kh0 pair (4 loads) in flight; drain in tail
        if (t + 2 < NT) asm volatile("s_waitcnt vmcnt(4)" ::: "memory");
        else            asm volatile("s_waitcnt vmcnt(0)" ::: "memory");
        __builtin_amdgcn_s_barrier();
        asm volatile("" ::: "memory");
    }

    // epilogue: row = row0 + wm*128 + mf*16 + quad*4 + r, col = col0 + wn*64 + nf*16 + lq
    const int part = xtile >> 2;   // 0=Q, 1=K, 2=V (block-uniform)
#pragma unroll
    for (int mf = 0; mf < 8; ++mf)
#pragma unroll
        for (int nf = 0; nf < 4; ++nf) {
            const int colp = (col0 & 1023) + wn * 64 + nf * 16 + lq;
            const int hh = colp >> 6, d = colp & 63;
#pragma unroll
            for (int r = 0; r < 4; ++r) {
                const int row = row0 + wm * 128 + mf * 16 + quad * 4 + r;
                const int b = row >> 11, tok = row & 2047;
                const int bh = b * 16 + hh;
                if (part == 0) {
                    Qh[((size_t)bh * 2048 + tok) * 64 + d] = bf1(acc[mf][nf][r] * SCALE_L2E);
                } else if (part == 1) {
                    Kh[((size_t)bh * 2048 + tok) * 64 + (d ^ ((tok & 7) << 3))] = bf1(acc[mf][nf][r]);
                } else {
                    VT[((size_t)bh * 64 + d) * 2048 + (tok ^ ((d & 7) << 3))] = bf1(acc[mf][nf][r]);
                }
            }
        }
}

// ---------------------------------------------------------------------------
// Flash attention, K-split=2, no running max. Block = 256 thr (4 waves),
// q-tile 128; wave w owns 32 q-rows. All K/V staging via global_load_lds
// (swizzled layouts baked in by the GEMM). Row-sums l via ones-row MFMA.
// Double-buffered, one barrier per tile. Dispatch: qt from bits 5-7
// complemented by bit 9 -> stride-256 CU residents {q,q,15-q,15-q}.
// ---------------------------------------------------------------------------
__global__ __launch_bounds__(256, 4) void attn_bf16(
    const ushort* __restrict__ Qh, const ushort* __restrict__ Kh,
    const ushort* __restrict__ VT, ushort* __restrict__ Opart, float* __restrict__ Lp)
{
    __shared__ __align__(16) ushort Ks[2][64 * 64];   // [krow][d^swz]
    __shared__ __align__(16) ushort Vt[2][64 * 64];   // [d][k^swz]

    const int x = blockIdx.x;
    const int bh = x & 31;
    const int qlow = (x >> 5) & 7;
    const int s = (x >> 8) & 1;
    const int x9 = (x >> 9) & 1;
    const int qt = x9 ? (15 - qlow) : qlow;

    const int tid = threadIdx.x;
    const int w = tid >> 6, lane = tid & 63;
    const int lq = lane & 15, quad = lane >> 4;
    const int kswz = (lq & 7) << 3;
    const int qrow_base = qt * 128 + w * 32;
    const int diag = 2 * qt + (w >> 1);

    s8v qf[2][2];
#pragma unroll
    for (int qg = 0; qg < 2; ++qg)
#pragma unroll
        for (int sb = 0; sb < 2; ++sb)
            qf[qg][sb] = *(const s8v*)(Qh + ((size_t)bh * 2048 + qrow_base + qg * 16 + lq) * 64
                                       + sb * 32 + quad * 8);

    f4v o[4][2];
#pragma unroll
    for (int dg = 0; dg < 4; ++dg)
#pragma unroll
        for (int qg = 0; qg < 2; ++qg) o[dg][qg] = 0.f;
    f4v lacc[2]; lacc[0] = 0.f; lacc[1] = 0.f;
    const s4v ones = { (short)0x3F80, (short)0x3F80, (short)0x3F80, (short)0x3F80 };

    const int kt_lo = s ? (qt + 1) : 0;
    const int kt_hi = s ? (2 * qt + 1) : qt;
    const int niter = kt_hi - kt_lo + 1;

    const ushort* kbase = Kh + (size_t)bh * 2048 * 64;
    const ushort* vbase = VT + (size_t)bh * 64 * 2048;
    const int g1 = tid, g2 = tid + 256;
    const int kr1 = g1 >> 3, ko1 = (g1 & 7) * 8;
    const int kr2 = g2 >> 3, ko2 = (g2 & 7) * 8;

    auto stage = [&](int kt, int bufi) {
        const ushort* kt_k = kbase + (size_t)kt * 64 * 64;
        const ushort* kt_v = vbase + kt * 64;
        gl_lds16(kt_k + kr1 * 64 + ko1,           &Ks[bufi][g1 * 8]);
        gl_lds16(kt_k + kr2 * 64 + ko2,           &Ks[bufi][g2 * 8]);
        gl_lds16(kt_v + (size_t)kr1 * 2048 + ko1, &Vt[bufi][g1 * 8]);
        gl_lds16(kt_v + (size_t)kr2 * 2048 + ko2, &Vt[bufi][g2 * 8]);
    };

    auto compute = [&](int ktc, int bufi) {
        if (ktc > diag) return;
        f4v st[4][2];
#pragma unroll
        for (int kg = 0; kg < 4; ++kg)
#pragma unroll
            for (int qg = 0; qg < 2; ++qg) st[kg][qg] = 0.f;
#pragma unroll
        for (int kg = 0; kg < 4; ++kg)
#pragma unroll
            for (int sb = 0; sb < 2; ++sb) {
                const s8v af = *(const s8v*)&Ks[bufi][(kg * 16 + lq) * 64
                                                     + ((sb * 32 + quad * 8) ^ kswz)];
#pragma unroll
                for (int qg = 0; qg < 2; ++qg)
                    st[kg][qg] = MFMA_16x16x32(af, qf[qg][sb], st[kg][qg]);
            }
        if (ktc == diag) {
#pragma unroll
            for (int kg = 0; kg < 4; ++kg)
#pragma unroll
                for (int qg = 0; qg < 2; ++qg) {
                    const int qrow = qrow_base + qg * 16 + lq;
#pragma unroll
                    for (int r = 0; r < 4; ++r)
                        if (ktc * 64 + kg * 16 + quad * 4 + r > qrow)
                            st[kg][qg][r] = -INFINITY;
                }
        }
#pragma unroll
        for (int kg = 0; kg < 4; ++kg)
#pragma unroll
            for (int qg = 0; qg < 2; ++qg)
#pragma unroll
                for (int r = 0; r < 4; ++r)
                    st[kg][qg][r] = exp2f(st[kg][qg][r]);
#pragma unroll
        for (int ks = 0; ks < 4; ++ks) {
            s4v pb[2];
#pragma unroll
            for (int qg = 0; qg < 2; ++qg) {
                union { s4v v; uint2 u; } c;
                c.u.x = bfpk(st[ks][qg][0], st[ks][qg][1]);
                c.u.y = bfpk(st[ks][qg][2], st[ks][qg][3]);
                pb[qg] = c.v;
            }
#pragma unroll
            for (int qg = 0; qg < 2; ++qg)
                lacc[qg] = MFMA_16x16x16(ones, pb[qg], lacc[qg]);
#pragma unroll
            for (int dg = 0; dg < 4; ++dg) {
                const s4v va = *(const s4v*)&Vt[bufi][(dg * 16 + lq) * 64
                                                     + ((ks * 16 + quad * 4) ^ kswz)];
#pragma unroll
                for (int qg = 0; qg < 2; ++qg)
                    o[dg][qg] = MFMA_16x16x16(va, pb[qg], o[dg][qg]);
            }
        }
    };

    stage(kt_lo, 0);
    for (int i = 0; i < niter; ++i) {
        const int cur = i & 1;
        __syncthreads();
        if (i + 1 < niter) stage(kt_lo + i + 1, cur ^ 1);
        compute(kt_lo + i, cur);
    }

#pragma unroll
    for (int qg = 0; qg < 2; ++qg) {
        const size_t prow = (size_t)(s * 32 + bh) * 2048 + qrow_base + qg * 16 + lq;
#pragma unroll
        for (int dg = 0; dg < 4; ++dg) {
            const int d = dg * 16 + quad * 4;
            uint2 u;
            u.x = bfpk(o[dg][qg][0], o[dg][qg][1]);
            u.y = bfpk(o[dg][qg][2], o[dg][qg][3]);
            *(uint2*)&Opart[prow * 64 + d] = u;
        }
        if (quad == 0) Lp[prow] = lacc[qg][0];
    }
}

// ---------------------------------------------------------------------------
// Combine the two K-split partials -> final f32 output [B, L, D].
// ---------------------------------------------------------------------------
__global__ __launch_bounds__(256) void attn_combine(
    const ushort* __restrict__ Opart, const float* __restrict__ Lp, float* __restrict__ Out)
{
    const int id = blockIdx.x * 256 + threadIdx.x;
    const int row = id >> 4, c4 = (id & 15) * 4;
    const float l0 = Lp[row], l1 = Lp[row + NROWS];
    const float inv = 1.0f / (l0 + l1);

    const s4v a = *(const s4v*)&Opart[(size_t)row * 64 + c4];
    const s4v c = *(const s4v*)&Opart[(size_t)(row + NROWS) * 64 + c4];
    float4 v;
    v.x = (bf2f((unsigned short)a[0]) + bf2f((unsigned short)c[0])) * inv;
    v.y = (bf2f((unsigned short)a[1]) + bf2f((unsigned short)c[1])) * inv;
    v.z = (bf2f((unsigned short)a[2]) + bf2f((unsigned short)c[2])) * inv;
    v.w = (bf2f((unsigned short)a[3]) + bf2f((unsigned short)c[3])) * inv;

    const int bh = row >> 11, qrow = row & 2047;
    const int b = bh >> 4, h = bh & 15;
    *(float4*)(Out + ((size_t)(b * 2048 + qrow)) * 1024 + h * 64 + c4) = v;
}

// ---------------------------------------------------------------------------
extern "C" void kernel_launch(void* const* d_in, const int* in_sizes, int n_in,
                              void* d_out, int out_size, void* d_ws, size_t ws_size,
                              hipStream_t stream)
{
    const float* x  = (const float*)d_in[0];  // [2,2048,1024] f32
    const float* wq = (const float*)d_in[1];  // [1024,3072] f32
    float* out = (float*)d_out;               // [2,2048,1024] f32

    const size_t HEADTEN = (size_t)32 * 2048 * 64;   // 8.4 MB bf16 each
    ushort* wsp = (ushort*)d_ws;
    ushort* qh = wsp;
    ushort* kh = qh + HEADTEN;
    ushort* vt = kh + HEADTEN;
    ushort* xb = vt + HEADTEN;           // dead after GEMM
    ushort* wt = xb + (size_t)GM * GK;   // dead after GEMM
    ushort* opart = xb;                                        // overlays xb/wt
    float*  lp    = (float*)(opart + (size_t)2 * NROWS * 64);

    conv_fused<<<2816, 256, 0, stream>>>(x, wq, xb, wt);
    qkv_gemm_bf16<<<192, 512, 0, stream>>>(xb, wt, qh, kh, vt);
    attn_bf16<<<1024, 256, 0, stream>>>(qh, kh, vt, opart, lp);
    attn_combine<<<NROWS * 16 / 256, 256, 0, stream>>>(opart, lp, out);
}

// Round 2
// 171.346 us; speedup vs baseline: 1.1105x; 1.0367x over previous
//
#include <hip/hip_runtime.h>
#include <hip/hip_bf16.h>
#include <math.h>

// B=2, L=2048, D=1024, H=16, HD=64
#define NB_L 2048
#define GM 4096          // B*L rows
#define GN 3072          // 3*D cols
#define GK 1024
#define NROWS 65536      // B*H*L partial rows per split
#define SCALE_L2E 0.180336880f   // 0.125 * log2(e), folded into Q at GEMM epilogue

typedef float  f4v __attribute__((ext_vector_type(4)));
typedef short  s4v __attribute__((ext_vector_type(4)));
typedef short  s8v __attribute__((ext_vector_type(8)));

#define MFMA_16x16x32(a, b, c) __builtin_amdgcn_mfma_f32_16x16x32_bf16((a), (b), (c), 0, 0, 0)
#define MFMA_16x16x16(a, b, c) __builtin_amdgcn_mfma_f32_16x16x16bf16_1k((a), (b), (c), 0, 0, 0)

static __device__ __forceinline__ unsigned int bfpk(float a, float b) {
    __hip_bfloat162 h = __float22bfloat162_rn(float2{a, b});
    union { __hip_bfloat162 h2; unsigned int u; } cv; cv.h2 = h; return cv.u;
}
static __device__ __forceinline__ unsigned short bf1(float a) {
    union { __hip_bfloat16 h; unsigned short u; } cv; cv.h = __float2bfloat16(a); return cv.u;
}
static __device__ __forceinline__ float bf2f(unsigned short u) {
    union { unsigned int u; float f; } cv; cv.u = ((unsigned int)u) << 16; return cv.f;
}

// async global->LDS, 16B per lane
static __device__ __forceinline__ void gl_lds16(const ushort* g, ushort* l) {
    __builtin_amdgcn_global_load_lds((const __attribute__((address_space(1))) void*)g,
                                     (__attribute__((address_space(3))) void*)l, 16, 0, 0);
}

// ---------------------------------------------------------------------------
// Fused input prep: blocks [0,2048) convert X f32->bf16; blocks [2048,2816)
// convert+transpose W -> Wt [3072,1024] bf16 (k contiguous).
// ---------------------------------------------------------------------------
__global__ __launch_bounds__(256) void conv_fused(
    const float* __restrict__ X, const float* __restrict__ W,
    ushort* __restrict__ Xb, ushort* __restrict__ Wt)
{
    __shared__ __align__(16) ushort T[64][72];
    const int bid = blockIdx.x, t = threadIdx.x;
    if (bid < 2048) {
        const int i = bid * 256 + t;
        const float4 f0 = ((const float4*)X)[2 * i];
        const float4 f1 = ((const float4*)X)[2 * i + 1];
        uint4 u;
        u.x = bfpk(f0.x, f0.y); u.y = bfpk(f0.z, f0.w);
        u.z = bfpk(f1.x, f1.y); u.w = bfpk(f1.z, f1.w);
        ((uint4*)Xb)[i] = u;
    } else {
        const int wb = bid - 2048;                 // 0..767
        const int k0 = (wb & 15) * 64, n0 = (wb >> 4) * 64;
        {
            const int kr = t >> 2, nc0 = (t & 3) * 16;
            const float* src = W + (size_t)(k0 + kr) * GN + n0 + nc0;
#pragma unroll
            for (int u = 0; u < 4; ++u) {
                const float4 v = *(const float4*)(src + 4 * u);
                T[nc0 + 4 * u + 0][kr] = bf1(v.x);
                T[nc0 + 4 * u + 1][kr] = bf1(v.y);
                T[nc0 + 4 * u + 2][kr] = bf1(v.z);
                T[nc0 + 4 * u + 3][kr] = bf1(v.w);
            }
        }
        __syncthreads();
        {
            const int nr = t >> 2, kc0 = (t & 3) * 16;
            ushort* dst = Wt + (size_t)(n0 + nr) * GK + k0 + kc0;
            *(s8v*)dst       = *(const s8v*)&T[nr][kc0];
            *(s8v*)(dst + 8) = *(const s8v*)&T[nr][kc0 + 8];
        }
    }
}

// ---------------------------------------------------------------------------
// bf16 MFMA GEMM — BM=128 x BN=192, BK=64, 256 thr (4 waves, 1M x 4N),
// 80 KiB LDS -> 2 blocks/CU (exactly 160 KiB), grid 32x16 = 512 = 2/CU.
// The second resident block hides the per-phase barrier/LDS serialization
// that capped the 1-block/CU 256^2 variant at MfmaUtil 17%.
//
// 8-phase counted-vmcnt schedule, staging unit = K-half (32 k):
//   A kh = 128x32x2B =  8 KB = 2 gl_lds issues (256 thr x 16B = 4 KB each)
//   B kh = 192x32x2B = 12 KB = 3 issues
// Per K-tile t (4 phases, 12 MFMA/wave each):
//   ph0: read B[ks0]x3 + A[lo,ks0]x4; stage B(t+1,kh1)x3
//   ph1: read A[hi,ks0]x4 (B reused);  stage A(t+1,kh1)x2
//   ph2: read B[ks1]x3 + A[lo,ks1]x4; stage A(t+2,kh0)x2  (into cur buf kh0)
//   ph3: read A[hi,ks1]x4;            stage B(t+2,kh0)x3
// each phase: {ds_reads; stage; barrier; lgkmcnt(0); setprio(1); MFMAs;
// setprio(0); barrier}. ONE vmcnt(5) per K-tile (end ph3): only the newest
// 5 loads (t+2 kh0 group) stay in flight -> never drained to 0 in steady
// state. kh0(t+2) overwrites cur-buf kh0, safe: last readers are ph0/ph1.
//
// Bank conflicts: chunk-XOR swizzle (phys chunk = logical ^ ((row>>1)&3)),
// applied as inverse-swizzled GLOBAL source + swizzled ds_read (linear
// gl_lds dest). Measured 0 conflicts in round 1 with this scheme.
//
// Grid 512, XCD region swizzle: xcd=bid%8 owns an 8x8 tile region.
// Epilogue layouts unchanged; part (Q/K/V) is per-nf-fragment uniform
// (16-col frags never cross the 1024 boundary).
// ---------------------------------------------------------------------------
__global__ __launch_bounds__(256, 2) void qkv_gemm_bf16(
    const ushort* __restrict__ Xb, const ushort* __restrict__ Wt,
    ushort* __restrict__ Qh, ushort* __restrict__ Kh, ushort* __restrict__ VT)
{
    __shared__ __align__(16) ushort As[2][2][128][32];   // 32 KB [buf][khalf][row][k]
    __shared__ __align__(16) ushort Bs[2][2][192][32];   // 48 KB

    const int tid = threadIdx.x;
    const int bid = blockIdx.x;

    // XCD region swizzle: tile grid 32(y) x 16(x); xcd owns 8x8 region
    const int xcd = bid & 7, idx = bid >> 3;             // idx in [0,64)
    const int ytile = ((xcd >> 1) << 3) + (idx & 7);     // 0..31
    const int xtile = ((xcd & 1) << 3) + (idx >> 3);     // 0..15
    const int row0 = ytile << 7;                         // *128
    const int col0 = xtile * 192;

    const int lane = tid & 63, wn = tid >> 6;            // 4 N-waves
    const int lq = lane & 15, quad = lane >> 4;

    // staging decomposition: thread -> (row-within-issue rS, physical chunk pA)
    const int rS = tid >> 2, pA = tid & 3;               // rS in [0,64)
    const int cA = pA ^ ((rS >> 1) & 3);                 // logical chunk (inverse swizzle)
    const ushort* gA0 = Xb + (size_t)(row0 + rS) * GK + cA * 8;
    const ushort* gB0 = Wt + (size_t)(col0 + rS) * GK + cA * 8;

    // frag-read physical chunk (element offset within 32-k row)
    const int pq = (quad ^ ((lq >> 1) & 3)) * 8;
    const int rowB = wn * 48;

    f4v acc[8][3];
#pragma unroll
    for (int mf = 0; mf < 8; ++mf)
#pragma unroll
        for (int nf = 0; nf < 3; ++nf) acc[mf][nf] = 0.f;

    auto stA = [&](int t, int h, int u) {
        gl_lds16(gA0 + (size_t)u * 64 * GK + t * 64 + h * 32,
                 &As[t & 1][h][u * 64 + rS][pA * 8]);
    };
    auto stB = [&](int t, int h, int u) {
        gl_lds16(gB0 + (size_t)u * 64 * GK + t * 64 + h * 32,
                 &Bs[t & 1][h][u * 64 + rS][pA * 8]);
    };

    // prologue: t0 fully + t1 kh0 last; allow the newest 5 (t1 kh0) in flight
    stA(0, 0, 0); stA(0, 0, 1);
    stB(0, 0, 0); stB(0, 0, 1); stB(0, 0, 2);
    stA(0, 1, 0); stA(0, 1, 1);
    stB(0, 1, 0); stB(0, 1, 1); stB(0, 1, 2);
    stA(1, 0, 0); stA(1, 0, 1);
    stB(1, 0, 0); stB(1, 0, 1); stB(1, 0, 2);
    asm volatile("s_waitcnt vmcnt(5)" ::: "memory");
    __builtin_amdgcn_s_barrier();
    asm volatile("" ::: "memory");

    const int NT = GK / 64;   // 16
#pragma unroll 2
    for (int t = 0; t < NT; ++t) {
        const int cur = t & 1;
        s8v af[4], bfr[3];

        // ---- phase 0: ks0, M-lo ----
#pragma unroll
        for (int nf = 0; nf < 3; ++nf) bfr[nf] = *(const s8v*)&Bs[cur][0][rowB + nf * 16 + lq][pq];
#pragma unroll
        for (int mf = 0; mf < 4; ++mf) af[mf] = *(const s8v*)&As[cur][0][mf * 16 + lq][pq];
        if (t + 1 < NT) { stB(t + 1, 1, 0); stB(t + 1, 1, 1); stB(t + 1, 1, 2); }
        __builtin_amdgcn_s_barrier();
        asm volatile("s_waitcnt lgkmcnt(0)");
        __builtin_amdgcn_s_setprio(1);
#pragma unroll
        for (int mf = 0; mf < 4; ++mf)
#pragma unroll
            for (int nf = 0; nf < 3; ++nf)
                acc[mf][nf] = MFMA_16x16x32(af[mf], bfr[nf], acc[mf][nf]);
        __builtin_amdgcn_s_setprio(0);
        __builtin_amdgcn_s_barrier();

        // ---- phase 1: ks0, M-hi (B frags reused) ----
#pragma unroll
        for (int mf = 0; mf < 4; ++mf) af[mf] = *(const s8v*)&As[cur][0][64 + mf * 16 + lq][pq];
        if (t + 1 < NT) { stA(t + 1, 1, 0); stA(t + 1, 1, 1); }
        __builtin_amdgcn_s_barrier();
        asm volatile("s_waitcnt lgkmcnt(0)");
        __builtin_amdgcn_s_setprio(1);
#pragma unroll
        for (int mf = 0; mf < 4; ++mf)
#pragma unroll
            for (int nf = 0; nf < 3; ++nf)
                acc[mf + 4][nf] = MFMA_16x16x32(af[mf], bfr[nf], acc[mf + 4][nf]);
        __builtin_amdgcn_s_setprio(0);
        __builtin_amdgcn_s_barrier();

        // ---- phase 2: ks1, M-lo ----
#pragma unroll
        for (int nf = 0; nf < 3; ++nf) bfr[nf] = *(const s8v*)&Bs[cur][1][rowB + nf * 16 + lq][pq];
#pragma unroll
        for (int mf = 0; mf < 4; ++mf) af[mf] = *(const s8v*)&As[cur][1][mf * 16 + lq][pq];
        if (t + 2 < NT) { stA(t + 2, 0, 0); stA(t + 2, 0, 1); }   // cur-buf kh0: last read ph1
        __builtin_amdgcn_s_barrier();
        asm volatile("s_waitcnt lgkmcnt(0)");
        __builtin_amdgcn_s_setprio(1);
#pragma unroll
        for (int mf = 0; mf < 4; ++mf)
#pragma unroll
            for (int nf = 0; nf < 3; ++nf)
                acc[mf][nf] = MFMA_16x16x32(af[mf], bfr[nf], acc[mf][nf]);
        __builtin_amdgcn_s_setprio(0);
        __builtin_amdgcn_s_barrier();

        // ---- phase 3: ks1, M-hi ----
#pragma unroll
        for (int mf = 0; mf < 4; ++mf) af[mf] = *(const s8v*)&As[cur][1][64 + mf * 16 + lq][pq];
        if (t + 2 < NT) { stB(t + 2, 0, 0); stB(t + 2, 0, 1); stB(t + 2, 0, 2); }
        __builtin_amdgcn_s_barrier();
        asm volatile("s_waitcnt lgkmcnt(0)");
        __builtin_amdgcn_s_setprio(1);
#pragma unroll
        for (int mf = 0; mf < 4; ++mf)
#pragma unroll
            for (int nf = 0; nf < 3; ++nf)
                acc[mf + 4][nf] = MFMA_16x16x32(af[mf], bfr[nf], acc[mf + 4][nf]);
        __builtin_amdgcn_s_setprio(0);
        // keep the newest 5 (t+2 kh0 group) in flight; drain only in tail
        if (t + 2 < NT) asm volatile("s_waitcnt vmcnt(5)" ::: "memory");
        else            asm volatile("s_waitcnt vmcnt(0)" ::: "memory");
        __builtin_amdgcn_s_barrier();
        asm volatile("" ::: "memory");
    }

    // epilogue: row = row0 + mf*16 + quad*4 + r, col = col0 + wn*48 + nf*16 + lq
#pragma unroll
    for (int mf = 0; mf < 8; ++mf)
#pragma unroll
        for (int nf = 0; nf < 3; ++nf) {
            const int colg = col0 + wn * 48 + nf * 16 + lq;
            const int part = colg >> 10;          // uniform per nf-frag (16 | 1024)
            const int colp = colg & 1023;
            const int hh = colp >> 6, d = colp & 63;
#pragma unroll
            for (int r = 0; r < 4; ++r) {
                const int row = row0 + mf * 16 + quad * 4 + r;
                const int b = row >> 11, tok = row & 2047;
                const int bh = b * 16 + hh;
                if (part == 0) {
                    Qh[((size_t)bh * 2048 + tok) * 64 + d] = bf1(acc[mf][nf][r] * SCALE_L2E);
                } else if (part == 1) {
                    Kh[((size_t)bh * 2048 + tok) * 64 + (d ^ ((tok & 7) << 3))] = bf1(acc[mf][nf][r]);
                } else {
                    VT[((size_t)bh * 64 + d) * 2048 + (tok ^ ((d & 7) << 3))] = bf1(acc[mf][nf][r]);
                }
            }
        }
}

// ---------------------------------------------------------------------------
// Flash attention, K-split=2, no running max. Block = 256 thr (4 waves),
// q-tile 128; wave w owns 32 q-rows. All K/V staging via global_load_lds
// (swizzled layouts baked in by the GEMM). Row-sums l via ones-row MFMA.
// Double-buffered, one barrier per tile. Dispatch: qt from bits 5-7
// complemented by bit 9 -> stride-256 CU residents {q,q,15-q,15-q}.
// ---------------------------------------------------------------------------
__global__ __launch_bounds__(256, 4) void attn_bf16(
    const ushort* __restrict__ Qh, const ushort* __restrict__ Kh,
    const ushort* __restrict__ VT, ushort* __restrict__ Opart, float* __restrict__ Lp)
{
    __shared__ __align__(16) ushort Ks[2][64 * 64];   // [krow][d^swz]
    __shared__ __align__(16) ushort Vt[2][64 * 64];   // [d][k^swz]

    const int x = blockIdx.x;
    const int bh = x & 31;
    const int qlow = (x >> 5) & 7;
    const int s = (x >> 8) & 1;
    const int x9 = (x >> 9) & 1;
    const int qt = x9 ? (15 - qlow) : qlow;

    const int tid = threadIdx.x;
    const int w = tid >> 6, lane = tid & 63;
    const int lq = lane & 15, quad = lane >> 4;
    const int kswz = (lq & 7) << 3;
    const int qrow_base = qt * 128 + w * 32;
    const int diag = 2 * qt + (w >> 1);

    s8v qf[2][2];
#pragma unroll
    for (int qg = 0; qg < 2; ++qg)
#pragma unroll
        for (int sb = 0; sb < 2; ++sb)
            qf[qg][sb] = *(const s8v*)(Qh + ((size_t)bh * 2048 + qrow_base + qg * 16 + lq) * 64
                                       + sb * 32 + quad * 8);

    f4v o[4][2];
#pragma unroll
    for (int dg = 0; dg < 4; ++dg)
#pragma unroll
        for (int qg = 0; qg < 2; ++qg) o[dg][qg] = 0.f;
    f4v lacc[2]; lacc[0] = 0.f; lacc[1] = 0.f;
    const s4v ones = { (short)0x3F80, (short)0x3F80, (short)0x3F80, (short)0x3F80 };

    const int kt_lo = s ? (qt + 1) : 0;
    const int kt_hi = s ? (2 * qt + 1) : qt;
    const int niter = kt_hi - kt_lo + 1;

    const ushort* kbase = Kh + (size_t)bh * 2048 * 64;
    const ushort* vbase = VT + (size_t)bh * 64 * 2048;
    const int g1 = tid, g2 = tid + 256;
    const int kr1 = g1 >> 3, ko1 = (g1 & 7) * 8;
    const int kr2 = g2 >> 3, ko2 = (g2 & 7) * 8;

    auto stage = [&](int kt, int bufi) {
        const ushort* kt_k = kbase + (size_t)kt * 64 * 64;
        const ushort* kt_v = vbase + kt * 64;
        gl_lds16(kt_k + kr1 * 64 + ko1,           &Ks[bufi][g1 * 8]);
        gl_lds16(kt_k + kr2 * 64 + ko2,           &Ks[bufi][g2 * 8]);
        gl_lds16(kt_v + (size_t)kr1 * 2048 + ko1, &Vt[bufi][g1 * 8]);
        gl_lds16(kt_v + (size_t)kr2 * 2048 + ko2, &Vt[bufi][g2 * 8]);
    };

    auto compute = [&](int ktc, int bufi) {
        if (ktc > diag) return;
        f4v st[4][2];
#pragma unroll
        for (int kg = 0; kg < 4; ++kg)
#pragma unroll
            for (int qg = 0; qg < 2; ++qg) st[kg][qg] = 0.f;
#pragma unroll
        for (int kg = 0; kg < 4; ++kg)
#pragma unroll
            for (int sb = 0; sb < 2; ++sb) {
                const s8v af = *(const s8v*)&Ks[bufi][(kg * 16 + lq) * 64
                                                     + ((sb * 32 + quad * 8) ^ kswz)];
#pragma unroll
                for (int qg = 0; qg < 2; ++qg)
                    st[kg][qg] = MFMA_16x16x32(af, qf[qg][sb], st[kg][qg]);
            }
        if (ktc == diag) {
#pragma unroll
            for (int kg = 0; kg < 4; ++kg)
#pragma unroll
                for (int qg = 0; qg < 2; ++qg) {
                    const int qrow = qrow_base + qg * 16 + lq;
#pragma unroll
                    for (int r = 0; r < 4; ++r)
                        if (ktc * 64 + kg * 16 + quad * 4 + r > qrow)
                            st[kg][qg][r] = -INFINITY;
                }
        }
#pragma unroll
        for (int kg = 0; kg < 4; ++kg)
#pragma unroll
            for (int qg = 0; qg < 2; ++qg)
#pragma unroll
                for (int r = 0; r < 4; ++r)
                    st[kg][qg][r] = exp2f(st[kg][qg][r]);
#pragma unroll
        for (int ks = 0; ks < 4; ++ks) {
            s4v pb[2];
#pragma unroll
            for (int qg = 0; qg < 2; ++qg) {
                union { s4v v; uint2 u; } c;
                c.u.x = bfpk(st[ks][qg][0], st[ks][qg][1]);
                c.u.y = bfpk(st[ks][qg][2], st[ks][qg][3]);
                pb[qg] = c.v;
            }
#pragma unroll
            for (int qg = 0; qg < 2; ++qg)
                lacc[qg] = MFMA_16x16x16(ones, pb[qg], lacc[qg]);
#pragma unroll
            for (int dg = 0; dg < 4; ++dg) {
                const s4v va = *(const s4v*)&Vt[bufi][(dg * 16 + lq) * 64
                                                     + ((ks * 16 + quad * 4) ^ kswz)];
#pragma unroll
                for (int qg = 0; qg < 2; ++qg)
                    o[dg][qg] = MFMA_16x16x16(va, pb[qg], o[dg][qg]);
            }
        }
    };

    stage(kt_lo, 0);
    for (int i = 0; i < niter; ++i) {
        const int cur = i & 1;
        __syncthreads();
        if (i + 1 < niter) stage(kt_lo + i + 1, cur ^ 1);
        compute(kt_lo + i, cur);
    }

#pragma unroll
    for (int qg = 0; qg < 2; ++qg) {
        const size_t prow = (size_t)(s * 32 + bh) * 2048 + qrow_base + qg * 16 + lq;
#pragma unroll
        for (int dg = 0; dg < 4; ++dg) {
            const int d = dg * 16 + quad * 4;
            uint2 u;
            u.x = bfpk(o[dg][qg][0], o[dg][qg][1]);
            u.y = bfpk(o[dg][qg][2], o[dg][qg][3]);
            *(uint2*)&Opart[prow * 64 + d] = u;
        }
        if (quad == 0) Lp[prow] = lacc[qg][0];
    }
}

// ---------------------------------------------------------------------------
// Combine the two K-split partials -> final f32 output [B, L, D].
// ---------------------------------------------------------------------------
__global__ __launch_bounds__(256) void attn_combine(
    const ushort* __restrict__ Opart, const float* __restrict__ Lp, float* __restrict__ Out)
{
    const int id = blockIdx.x * 256 + threadIdx.x;
    const int row = id >> 4, c4 = (id & 15) * 4;
    const float l0 = Lp[row], l1 = Lp[row + NROWS];
    const float inv = 1.0f / (l0 + l1);

    const s4v a = *(const s4v*)&Opart[(size_t)row * 64 + c4];
    const s4v c = *(const s4v*)&Opart[(size_t)(row + NROWS) * 64 + c4];
    float4 v;
    v.x = (bf2f((unsigned short)a[0]) + bf2f((unsigned short)c[0])) * inv;
    v.y = (bf2f((unsigned short)a[1]) + bf2f((unsigned short)c[1])) * inv;
    v.z = (bf2f((unsigned short)a[2]) + bf2f((unsigned short)c[2])) * inv;
    v.w = (bf2f((unsigned short)a[3]) + bf2f((unsigned short)c[3])) * inv;

    const int bh = row >> 11, qrow = row & 2047;
    const int b = bh >> 4, h = bh & 15;
    *(float4*)(Out + ((size_t)(b * 2048 + qrow)) * 1024 + h * 64 + c4) = v;
}

// ---------------------------------------------------------------------------
extern "C" void kernel_launch(void* const* d_in, const int* in_sizes, int n_in,
                              void* d_out, int out_size, void* d_ws, size_t ws_size,
                              hipStream_t stream)
{
    const float* x  = (const float*)d_in[0];  // [2,2048,1024] f32
    const float* wq = (const float*)d_in[1];  // [1024,3072] f32
    float* out = (float*)d_out;               // [2,2048,1024] f32

    const size_t HEADTEN = (size_t)32 * 2048 * 64;   // 8.4 MB bf16 each
    ushort* wsp = (ushort*)d_ws;
    ushort* qh = wsp;
    ushort* kh = qh + HEADTEN;
    ushort* vt = kh + HEADTEN;
    ushort* xb = vt + HEADTEN;           // dead after GEMM
    ushort* wt = xb + (size_t)GM * GK;   // dead after GEMM
    ushort* opart = xb;                                        // overlays xb/wt
    float*  lp    = (float*)(opart + (size_t)2 * NROWS * 64);

    conv_fused<<<2816, 256, 0, stream>>>(x, wq, xb, wt);
    qkv_gemm_bf16<<<512, 256, 0, stream>>>(xb, wt, qh, kh, vt);
    attn_bf16<<<1024, 256, 0, stream>>>(qh, kh, vt, opart, lp);
    attn_combine<<<NROWS * 16 / 256, 256, 0, stream>>>(opart, lp, out);
}